// Round 1
// baseline (580.008 us; speedup 1.0000x reference)
//
#include <hip/hip_runtime.h>
#include <hip/hip_cooperative_groups.h>

namespace cg = cooperative_groups;

#define BB 4
#define NN 8
#define HH 512
#define WW 512
#define CC 65536
#define EPSF 1e-10f
#define NF 15      // attrs inner dim
#define NFE 17     // feature count after log-scaling
#define MLOW 4096  // low-segment size, exact sums precomputed per tree
#define PSENT 0xFFFFu

#define THREADS 1024
#define SCHUNKS 8              // 8192 nodes/block in phases S and C
#define STG4 (THREADS * NF / 4) // 3840 float4 per 1024-node chunk

// packed node: high 16 = bf16 w, low 16 = parent (PSENT for node 0)
typedef unsigned int PN;

typedef int   nint4   __attribute__((ext_vector_type(4)));
typedef float nfloat4 __attribute__((ext_vector_type(4)));

__device__ inline unsigned short f2bf(float f) { // RNE bf16
    union { float f; unsigned u; } t; t.f = f;
    unsigned u = t.u;
    return (unsigned short)((u + 0x7fffu + ((u >> 16) & 1u)) >> 16);
}
__device__ inline float bf2f(unsigned short h) { // exact
    union { unsigned u; float f; } t; t.u = ((unsigned)h) << 16;
    return t.f;
}
__device__ inline float pn_w(PN v) { return bf2f((unsigned short)(v >> 16)); }
__device__ inline unsigned pn_p(PN v) { return v & 0xFFFFu; }

// Single fused cooperative kernel. 256 blocks x 1024 threads, 1 block/CU
// (128 KB LDS). Block mapping is XCD-affine: bid&7 = XCD (round-robin
// heuristic), each XCD serves 4 trees (1 MB packed wp) so all inter-phase
// traffic (wp, valLow, valh) stays in that XCD's L2. Correctness does NOT
// depend on the mapping: grid.sync() + device fences give visibility.
__global__ __launch_bounds__(THREADS) void k_fused(
    const float* __restrict__ diff, const float* __restrict__ attrs,
    const float* __restrict__ weight, const float* __restrict__ bias,
    const int* __restrict__ parent, const int* __restrict__ pix,
    float* __restrict__ out,
    PN* __restrict__ wp, float* __restrict__ valLow,
    unsigned short* __restrict__ valh)
{
    // 128 KB, aliased: phase S = 2 x 61440 B attrs staging; phase G = bf16 val table
    __shared__ __align__(16) unsigned short sval[CC];

    const int tid  = threadIdx.x;
    const int bid  = blockIdx.x;      // 0..255
    const int x    = bid & 7;         // XCD (heuristic)
    const int j    = bid >> 3;        // 0..31
    const int tree = x * 4 + (j & 3); // 0..31, 8 blocks/tree, all same XCD
    const int g    = j >> 2;          // 0..7  block-slice within tree
    const int n    = tree & 7;        // weight row
    const long long tbase = (long long)tree << 16;

    cg::grid_group grid = cg::this_grid();

    // ---------------- Phase S: score + pack ----------------
    float* sat = (float*)sval; // double buffer: sat + (c&1)*THREADS*NF
    float wgt[NFE];
    #pragma unroll
    for (int k = 0; k < NFE; ++k) wgt[k] = weight[n * NFE + k];
    const float bia = bias[n];

    nfloat4 r[4];
    { // prologue: load chunk 0 -> regs -> buf0
        const nfloat4* src = (const nfloat4*)(attrs + (tbase + (long long)g * 8192) * NF);
        #pragma unroll
        for (int i = 0; i < 4; ++i) {
            int k = tid + i * THREADS;
            if (k < STG4) r[i] = __builtin_nontemporal_load(src + k);
        }
        nfloat4* dst = (nfloat4*)sat;
        #pragma unroll
        for (int i = 0; i < 4; ++i) {
            int k = tid + i * THREADS;
            if (k < STG4) dst[k] = r[i];
        }
    }

    for (int c = 0; c < SCHUNKS; ++c) {
        __syncthreads(); // buf[c&1] ready; prior iter's readers done with buf[(c+1)&1]

        // T14: issue next chunk's global loads early (hide under math below)
        if (c + 1 < SCHUNKS) {
            const nfloat4* src = (const nfloat4*)(attrs +
                (tbase + (long long)g * 8192 + (long long)(c + 1) * THREADS) * NF);
            #pragma unroll
            for (int i = 0; i < 4; ++i) {
                int k = tid + i * THREADS;
                if (k < STG4) r[i] = __builtin_nontemporal_load(src + k);
            }
        }

        // stride 15 -> exactly 2 lanes/bank (free on CDNA4)
        const float* sf = sat + (c & 1) * (THREADS * NF);
        float f[NF];
        #pragma unroll
        for (int q = 0; q < NF; ++q) f[q] = sf[tid * NF + q];

        float logit = bia;
        logit = fmaf(f[0], wgt[0], logit);
        logit = fmaf(f[1], wgt[1], logit);
        logit = fmaf(f[2], wgt[2], logit);
        logit = fmaf(f[3], wgt[3], logit);
        logit = fmaf(__logf(f[4]), wgt[4], logit);   // area > 1
        #pragma unroll
        for (int q = 0; q < 9; ++q) {
            float xv = f[6 + q];
            float lg = __logf(fabsf(xv) + EPSF);
            float t = (xv > 0.f) ? lg : ((xv < 0.f) ? -lg : 0.f); // sign(0)=0
            logit = fmaf(t, wgt[5 + q], logit);
        }
        logit = fmaf(sqrtf(f[7]) * __frcp_rn(sqrtf(f[6]) + EPSF), wgt[14], logit);
        logit = fmaf(__cosf(f[5]), wgt[15], logit);  // angle in (-pi/2, pi/2)
        logit = fmaf(__sinf(f[5]), wgt[16], logit);

        const float score = __frcp_rn(1.f + __expf(-logit));
        const long long node = (long long)g * 8192 + (long long)c * THREADS + tid;
        const long long idx  = tbase + node;
        const float w = __builtin_nontemporal_load(diff + idx) * score;
        const int   p = __builtin_nontemporal_load(parent + idx); // == CC only at node 0
        const unsigned p16 = (p >= CC) ? PSENT : (unsigned)p;
        wp[idx] = ((unsigned)f2bf(w) << 16) | p16; // cached store: reused from L2

        // write-late: park next chunk into the other buffer
        if (c + 1 < SCHUNKS) {
            nfloat4* dst = (nfloat4*)(sat + ((c + 1) & 1) * (THREADS * NF));
            #pragma unroll
            for (int i = 0; i < 4; ++i) {
                int k = tid + i * THREADS;
                if (k < STG4) dst[k] = r[i];
            }
        }
    }

    __threadfence();
    grid.sync();

    // ---------------- Phase L: exact low-node ancestor sums ----------------
    // 512 low nodes per block (this tree's [g*512, g*512+512)); 16 KB packed
    // low window per tree is L1-resident.
    if (tid < 512) {
        const int node = g * 512 + tid;
        PN cur = wp[tbase + node];
        float acc = pn_w(cur);
        unsigned p = pn_p(cur);
        while (p != PSENT) { // node 0 -> sentinel
            PN nx = wp[tbase + p];
            acc += pn_w(nx);
            p = pn_p(nx);
        }
        valLow[((long long)tree << 12) + node] = acc;
    }

    __threadfence();
    grid.sync();

    // ---------------- Phase C: full ancestor sums -> bf16 ----------------
    // Nodes >= MLOW walk (~2.8 hops mean) until pointer < MLOW; hops hit this
    // XCD's L2 (1 MB window).
    const float* vlow = valLow + ((long long)tree << 12);
    for (int it = 0; it < SCHUNKS; ++it) {
        const int node0 = g * 8192 + it * THREADS + tid;
        float acc;
        if (node0 < MLOW) {
            acc = vlow[node0];
        } else {
            PN cur = wp[tbase + node0]; // coalesced
            acc = pn_w(cur);
            unsigned p = pn_p(cur);
            while (p >= MLOW) {
                PN nx = wp[tbase + p]; // 4B touch, L2-resident
                acc += pn_w(nx);
                p = pn_p(nx);
            }
            acc += vlow[p];
        }
        valh[tbase + node0] = f2bf(acc); // cached store: re-read next phase from L2
    }

    __threadfence();
    grid.sync();

    // ---------------- Phase G: pixel gather ----------------
    // Stage this tree's bf16 val table (128 KB) from L2 into LDS, then stream
    // pixels nontemporally. seg = g covers 32768 pixels.
    {
        const uint4* s4 = (const uint4*)(valh + tbase);
        uint4* d4 = (uint4*)sval;
        #pragma unroll
        for (int i = 0; i < 8; ++i)
            d4[tid + i * THREADS] = s4[tid + i * THREADS];
        __syncthreads();

        const long long pbase = ((long long)tree << 18) + ((long long)g << 15);
        const nint4*   psrc = (const nint4*)(pix + pbase);
        nfloat4*       pdst = (nfloat4*)(out + pbase);
        #pragma unroll 4
        for (int it = 0; it < 8; ++it) {
            const int i4 = tid + it * THREADS;
            nint4 cc = __builtin_nontemporal_load(psrc + i4);
            nfloat4 o;
            o.x = bf2f(sval[cc.x]) * 0.1f;
            o.y = bf2f(sval[cc.y]) * 0.1f;
            o.z = bf2f(sval[cc.z]) * 0.1f;
            o.w = bf2f(sval[cc.w]) * 0.1f;
            __builtin_nontemporal_store(o, pdst + i4);
        }
    }
}

extern "C" void kernel_launch(void* const* d_in, const int* in_sizes, int n_in,
                              void* d_out, int out_size, void* d_ws, size_t ws_size,
                              hipStream_t stream) {
    const float* diff   = (const float*)d_in[0];
    const float* attrs  = (const float*)d_in[1];
    const float* weight = (const float*)d_in[2];
    const float* bias   = (const float*)d_in[3];
    const int*   parent = (const int*)d_in[4];
    const int*   pix    = (const int*)d_in[5];
    float* out = (float*)d_out;

    // ws layout: [wp packed: 8MB][valh: 4MB][valLow: 512KB]
    PN*             wp     = (PN*)d_ws;
    unsigned short* valh   = (unsigned short*)((char*)d_ws + (size_t)BB * NN * CC * sizeof(PN));
    float*          valLow = (float*)((char*)valh + (size_t)BB * NN * CC * sizeof(unsigned short));

    void* args[] = { (void*)&diff, (void*)&attrs, (void*)&weight, (void*)&bias,
                     (void*)&parent, (void*)&pix, (void*)&out,
                     (void*)&wp, (void*)&valLow, (void*)&valh };
    hipLaunchCooperativeKernel((void*)k_fused, dim3(256), dim3(THREADS), args, 0, stream);
}

// Round 2
// 244.168 us; speedup vs baseline: 2.3754x; 2.3754x over previous
//
#include <hip/hip_runtime.h>

#define BB 4
#define NN 8
#define HH 512
#define WW 512
#define CC 65536
#define EPSF 1e-10f
#define NF 15     // attrs inner dim
#define NFE 17    // feature count after log-scaling
#define MLOW 8192 // low-segment size precomputed exactly per tree (2^13)
#define PSENT 0xFFFFu // packed parent sentinel (never a legal parent: max 65534)

// packed node: high 16 = bf16 w, low 16 = parent (PSENT for node 0)
typedef unsigned int PN;

// native clang vector types for nontemporal builtins
typedef int   nint4   __attribute__((ext_vector_type(4)));
typedef float nfloat4 __attribute__((ext_vector_type(4)));

__device__ inline unsigned short f2bf(float f) { // RNE bf16
    union { float f; unsigned u; } t; t.f = f;
    unsigned u = t.u;
    return (unsigned short)((u + 0x7fffu + ((u >> 16) & 1u)) >> 16);
}
__device__ inline float bf2f(unsigned short h) { // exact
    union { unsigned u; float f; } t; t.u = ((unsigned)h) << 16;
    return t.f;
}
__device__ inline float pn_w(PN v) { return bf2f((unsigned short)(v >> 16)); }
__device__ inline unsigned pn_p(PN v) { return v & 0xFFFFu; }

// Kernel 1: w = diff * sigmoid(feats . weight[n] + bias[n]); pack {w, parent}
// into 4 B/node. 15.4 KB LDS -> 10 blocks/CU -> 32 waves/CU (proven config).
__global__ __launch_bounds__(256) void k_score(
    const float* __restrict__ diff, const float* __restrict__ attrs,
    const float* __restrict__ weight, const float* __restrict__ bias,
    const int* __restrict__ parent, PN* __restrict__ wp)
{
    __shared__ float sat[256 * NF]; // 15360 B
    const int tid = threadIdx.x;
    const long long base = (long long)blockIdx.x * 256;
    const int n = (int)((base / CC) % NN);

    // Coalesced float4 staging of this block's 256*15 attrs into LDS.
    // Nontemporal: attrs is a pure 126 MB stream, zero reuse.
    const nfloat4* src = (const nfloat4*)(attrs + base * NF);
    nfloat4* dst4 = (nfloat4*)sat;
    #pragma unroll
    for (int i = 0; i < 4; ++i) {
        int k = tid + i * 256;
        if (k < (256 * NF) / 4) dst4[k] = __builtin_nontemporal_load(src + k);
    }
    __syncthreads();

    // stride 15 -> exactly 2 lanes/bank (free on CDNA4)
    float f[NF];
    #pragma unroll
    for (int j = 0; j < NF; ++j) f[j] = sat[tid * NF + j];

    float wgt[NFE];
    #pragma unroll
    for (int k = 0; k < NFE; ++k) wgt[k] = weight[n * NFE + k];

    float logit = bias[n];
    logit = fmaf(f[0], wgt[0], logit);
    logit = fmaf(f[1], wgt[1], logit);
    logit = fmaf(f[2], wgt[2], logit);
    logit = fmaf(f[3], wgt[3], logit);
    logit = fmaf(__logf(f[4]), wgt[4], logit);   // area > 1
    #pragma unroll
    for (int j = 0; j < 9; ++j) {
        float x = f[6 + j];
        float lg = __logf(fabsf(x) + EPSF);
        float t = (x > 0.f) ? lg : ((x < 0.f) ? -lg : 0.f); // sign(0)=0
        logit = fmaf(t, wgt[5 + j], logit);
    }
    logit = fmaf(sqrtf(f[7]) * __frcp_rn(sqrtf(f[6]) + EPSF), wgt[14], logit);
    // angle in (-pi/2, pi/2): no range-reduction concerns for fast sin/cos
    logit = fmaf(__cosf(f[5]), wgt[15], logit);
    logit = fmaf(__sinf(f[5]), wgt[16], logit);

    const float score = __frcp_rn(1.f + __expf(-logit));
    const long long idx = base + tid;
    const float w = diff[idx] * score;
    const int p = parent[idx];                  // == CC only at node 0
    const unsigned p16 = (p >= CC) ? PSENT : (unsigned)p;
    wp[idx] = ((unsigned)f2bf(w) << 16) | p16;
}

// Kernel 2: exact ancestor sums for nodes [0, MLOW) of each tree, by direct
// chain walk (one thread per low node); the packed low window is 32 KB/tree
// -> L1-resident.
__global__ __launch_bounds__(256) void k_low(
    const PN* __restrict__ wp, float* __restrict__ valLow)
{
    const int i = blockIdx.x * 256 + threadIdx.x; // 0 .. 32*MLOW-1
    const int tree = i >> 13;                     // MLOW = 8192 = 2^13
    const int node = i & (MLOW - 1);
    const long long tbase = (long long)tree << 16;
    PN cur = wp[tbase + node]; // coalesced
    float acc = pn_w(cur);
    unsigned p = pn_p(cur);
    while (p != PSENT) {       // node 0 -> sentinel
        PN nx = wp[tbase + p];
        acc += pn_w(nx);
        p = pn_p(nx);
    }
    valLow[i] = acc;
}

// Kernel 3: full ancestor sums -> bf16. FOUR independent walks per thread in
// a lockstep predicated loop: 4 L2 loads in flight per lane (4x MLP) instead
// of one dependent chain. Groups of 1024 nodes are MLOW-aligned, so a block
// is uniformly all-low (direct valLow copy) or all-high (walk).
// XCD-affine: bid&7 = XCD, each XCD serves trees 4x..4x+3.
__global__ __launch_bounds__(256) void k_chain(
    const PN* __restrict__ wp, const float* __restrict__ valLow,
    unsigned short* __restrict__ valh)
{
    const int bid  = blockIdx.x;            // 0..2047
    const int x    = bid & 7;
    const int j    = bid >> 3;              // 0..255
    const int tree = (x << 2) + (j & 3);    // 0..31
    const int grp  = j >> 2;                // 0..63, 1024 nodes each
    const long long tbase = (long long)tree << 16;
    const float* vlow = valLow + ((long long)tree << 13);
    const int n0 = (grp << 10) + threadIdx.x;

    if ((grp << 10) < MLOW) {
        // all-low group: exact sums already in valLow
        #pragma unroll
        for (int s = 0; s < 4; ++s) {
            const int nd = n0 + s * 256;
            valh[tbase + nd] = f2bf(vlow[nd]);
        }
        return;
    }

    float    a0, a1, a2, a3;
    unsigned p0, p1, p2, p3;
    {
        PN c0 = wp[tbase + n0];         // 4 coalesced loads
        PN c1 = wp[tbase + n0 + 256];
        PN c2 = wp[tbase + n0 + 512];
        PN c3 = wp[tbase + n0 + 768];
        a0 = pn_w(c0); p0 = pn_p(c0);
        a1 = pn_w(c1); p1 = pn_p(c1);
        a2 = pn_w(c2); p2 = pn_p(c2);
        a3 = pn_w(c3); p3 = pn_p(c3);
    }
    // lockstep: up to 4 independent L2 loads issued per iteration
    while ((p0 >= MLOW) | (p1 >= MLOW) | (p2 >= MLOW) | (p3 >= MLOW)) {
        if (p0 >= MLOW) { PN nx = wp[tbase + p0]; a0 += pn_w(nx); p0 = pn_p(nx); }
        if (p1 >= MLOW) { PN nx = wp[tbase + p1]; a1 += pn_w(nx); p1 = pn_p(nx); }
        if (p2 >= MLOW) { PN nx = wp[tbase + p2]; a2 += pn_w(nx); p2 = pn_p(nx); }
        if (p3 >= MLOW) { PN nx = wp[tbase + p3]; a3 += pn_w(nx); p3 = pn_p(nx); }
    }
    // vlow window is 32 KB -> L1-resident random reads
    valh[tbase + n0      ] = f2bf(a0 + vlow[p0]);
    valh[tbase + n0 + 256] = f2bf(a1 + vlow[p1]);
    valh[tbase + n0 + 512] = f2bf(a2 + vlow[p2]);
    valh[tbase + n0 + 768] = f2bf(a3 + vlow[p3]);
}

// Kernel 4: out[i] = val[bn, pix2cc[i]] / 10. Whole tree's bf16 val table
// (128 KB) staged in LDS; pix/out are pure nontemporal HBM streams.
// 1024 threads (16 waves/CU at the forced 1 block/CU) for latency hiding.
// XCD-affine mapping matches k_chain's writers.
__global__ __launch_bounds__(1024) void k_gather(
    const unsigned short* __restrict__ valh, const int* __restrict__ pix,
    float* __restrict__ out)
{
    __shared__ unsigned short sval[CC]; // 128 KB of 160 KB/CU
    const int bid  = blockIdx.x;            // 0..255
    const int x    = bid & 7;
    const int r    = bid >> 3;              // 0..31
    const int tree = (x << 2) + (r & 3);    // same XCD as k_chain's writer
    const int seg  = r >> 2;                // 0..7

    // stage: 65536 ushorts = 8192 uint4; 1024 threads x 8 iters, coalesced
    const uint4* s4 = (const uint4*)(valh + ((long long)tree << 16));
    uint4* d4 = (uint4*)sval;
    #pragma unroll
    for (int i = 0; i < 8; ++i)
        d4[threadIdx.x + i * 1024] = s4[threadIdx.x + i * 1024];
    __syncthreads();

    // segment covers 32768 pixels: 1024 threads x 8 int4 iterations
    const long long pbase = ((long long)tree << 18) + ((long long)seg << 15);
    const nint4*   psrc = (const nint4*)(pix + pbase);
    nfloat4*       pdst = (nfloat4*)(out + pbase);
    #pragma unroll 4
    for (int it = 0; it < 8; ++it) {
        const int i4 = threadIdx.x + it * 1024;
        nint4 cc = __builtin_nontemporal_load(psrc + i4);
        nfloat4 o;
        o.x = bf2f(sval[cc.x]) * 0.1f;
        o.y = bf2f(sval[cc.y]) * 0.1f;
        o.z = bf2f(sval[cc.z]) * 0.1f;
        o.w = bf2f(sval[cc.w]) * 0.1f;
        __builtin_nontemporal_store(o, pdst + i4);
    }
}

extern "C" void kernel_launch(void* const* d_in, const int* in_sizes, int n_in,
                              void* d_out, int out_size, void* d_ws, size_t ws_size,
                              hipStream_t stream) {
    const float* diff   = (const float*)d_in[0];
    const float* attrs  = (const float*)d_in[1];
    const float* weight = (const float*)d_in[2];
    const float* bias   = (const float*)d_in[3];
    const int*   parent = (const int*)d_in[4];
    const int*   pix    = (const int*)d_in[5];
    float* out = (float*)d_out;

    // ws layout: [wp packed: 8MB][valh: 4MB][valLow: 1MB]
    PN*             wp     = (PN*)d_ws;
    unsigned short* valh   = (unsigned short*)((char*)d_ws + (size_t)BB * NN * CC * sizeof(PN));
    float*          valLow = (float*)((char*)valh + (size_t)BB * NN * CC * sizeof(unsigned short));

    const long long total = (long long)BB * NN * CC;      // 2,097,152

    k_score <<<(int)(total / 256), 256, 0, stream>>>(diff, attrs, weight, bias, parent, wp);
    k_low   <<<(BB * NN * MLOW) / 256, 256, 0, stream>>>(wp, valLow);
    k_chain <<<(int)(total / 1024), 256, 0, stream>>>(wp, valLow, valh);
    k_gather<<<BB * NN * 8, 1024, 0, stream>>>(valh, pix, out);
}

// Round 3
// 240.180 us; speedup vs baseline: 2.4149x; 1.0166x over previous
//
#include <hip/hip_runtime.h>

#define BB 4
#define NN 8
#define HH 512
#define WW 512
#define CC 65536
#define EPSF 1e-10f
#define NF 15     // attrs inner dim
#define NFE 17    // feature count after log-scaling
#define MLOW 8192 // low-segment size precomputed exactly per tree (2^13)
#define PSENT 0xFFFFu // packed parent sentinel (never a legal parent: max 65534)

// packed node: high 16 = bf16 w, low 16 = parent (PSENT for node 0)
typedef unsigned int PN;

// native clang vector types for nontemporal builtins
typedef int   nint4   __attribute__((ext_vector_type(4)));
typedef float nfloat4 __attribute__((ext_vector_type(4)));

__device__ inline unsigned short f2bf(float f) { // RNE bf16
    union { float f; unsigned u; } t; t.f = f;
    unsigned u = t.u;
    return (unsigned short)((u + 0x7fffu + ((u >> 16) & 1u)) >> 16);
}
__device__ inline float bf2f(unsigned short h) { // exact
    union { unsigned u; float f; } t; t.u = ((unsigned)h) << 16;
    return t.f;
}
__device__ inline float pn_w(PN v) { return bf2f((unsigned short)(v >> 16)); }
__device__ inline unsigned pn_p(PN v) { return v & 0xFFFFu; }

// Kernel 1: w = diff * sigmoid(feats . weight[n] + bias[n]); pack {w, parent}
// into 4 B/node. 15.4 KB LDS -> 8+ blocks/CU -> 32 waves/CU.
// diff/parent loads issued BEFORE the barrier: their HBM latency hides under
// the attrs stage wait (compiler cannot hoist loads over __syncthreads).
__global__ __launch_bounds__(256) void k_score(
    const float* __restrict__ diff, const float* __restrict__ attrs,
    const float* __restrict__ weight, const float* __restrict__ bias,
    const int* __restrict__ parent, PN* __restrict__ wp)
{
    __shared__ float sat[256 * NF]; // 15360 B
    const int tid = threadIdx.x;
    const long long base = (long long)blockIdx.x * 256;
    const int n = (int)((base / CC) % NN);
    const long long idx = base + tid;

    // Coalesced float4 staging of this block's 256*15 attrs into LDS.
    // Nontemporal: attrs is a pure 126 MB stream, zero reuse.
    const nfloat4* src = (const nfloat4*)(attrs + base * NF);
    nfloat4* dst4 = (nfloat4*)sat;
    #pragma unroll
    for (int i = 0; i < 4; ++i) {
        int k = tid + i * 256;
        if (k < (256 * NF) / 4) dst4[k] = __builtin_nontemporal_load(src + k);
    }
    // issue-early: independent of LDS, overlap with stage drain + barrier
    const float dv = __builtin_nontemporal_load(diff + idx);
    const int   p  = __builtin_nontemporal_load(parent + idx); // == CC only at node 0
    __syncthreads();

    // stride 15 -> exactly 2 lanes/bank (free on CDNA4)
    float f[NF];
    #pragma unroll
    for (int j = 0; j < NF; ++j) f[j] = sat[tid * NF + j];

    float wgt[NFE];
    #pragma unroll
    for (int k = 0; k < NFE; ++k) wgt[k] = weight[n * NFE + k];

    float logit = bias[n];
    logit = fmaf(f[0], wgt[0], logit);
    logit = fmaf(f[1], wgt[1], logit);
    logit = fmaf(f[2], wgt[2], logit);
    logit = fmaf(f[3], wgt[3], logit);
    logit = fmaf(__logf(f[4]), wgt[4], logit);   // area > 1
    #pragma unroll
    for (int j = 0; j < 9; ++j) {
        float x = f[6 + j];
        float lg = __logf(fabsf(x) + EPSF);
        float t = (x > 0.f) ? lg : ((x < 0.f) ? -lg : 0.f); // sign(0)=0
        logit = fmaf(t, wgt[5 + j], logit);
    }
    logit = fmaf(sqrtf(f[7]) * __frcp_rn(sqrtf(f[6]) + EPSF), wgt[14], logit);
    // angle in (-pi/2, pi/2): no range-reduction concerns for fast sin/cos
    logit = fmaf(__cosf(f[5]), wgt[15], logit);
    logit = fmaf(__sinf(f[5]), wgt[16], logit);

    const float score = __frcp_rn(1.f + __expf(-logit));
    const float w = dv * score;
    const unsigned p16 = (p >= CC) ? PSENT : (unsigned)p;
    wp[idx] = ((unsigned)f2bf(w) << 16) | p16;
}

// Kernel 2: exact ancestor sums for nodes [0, MLOW) of each tree, by direct
// chain walk (one thread per low node); the packed low window is 32 KB/tree
// -> L1-resident. Writes BOTH valLow (f32, for k_chain's terminal lookup)
// and valh (bf16 final output for low nodes) -- removes the low-copy blocks
// from k_chain entirely.
__global__ __launch_bounds__(256) void k_low(
    const PN* __restrict__ wp, float* __restrict__ valLow,
    unsigned short* __restrict__ valh)
{
    const int i = blockIdx.x * 256 + threadIdx.x; // 0 .. 32*MLOW-1
    const int tree = i >> 13;                     // MLOW = 8192 = 2^13
    const int node = i & (MLOW - 1);
    const long long tbase = (long long)tree << 16;
    PN cur = wp[tbase + node]; // coalesced
    float acc = pn_w(cur);
    unsigned p = pn_p(cur);
    while (p != PSENT) {       // node 0 -> sentinel
        PN nx = wp[tbase + p];
        acc += pn_w(nx);
        p = pn_p(nx);
    }
    valLow[i] = acc;
    valh[tbase + node] = f2bf(acc);
}

// Kernel 3: high-node ancestor sums -> bf16. FOUR independent walks per
// thread in a lockstep predicated loop: 4 L2 loads in flight per lane.
// Grid covers ONLY high groups (56 per tree); low nodes were written by
// k_low. XCD-affine: bid&7 = XCD, each XCD serves trees 4x..4x+3.
__global__ __launch_bounds__(256) void k_chain(
    const PN* __restrict__ wp, const float* __restrict__ valLow,
    unsigned short* __restrict__ valh)
{
    const int bid  = blockIdx.x;            // 0..1791
    const int x    = bid & 7;
    const int j    = bid >> 3;              // 0..223
    const int tree = (x << 2) + (j & 3);    // 0..31
    const int grp  = 8 + (j >> 2);          // 8..63, 1024 nodes each (high only)
    const long long tbase = (long long)tree << 16;
    const float* vlow = valLow + ((long long)tree << 13);
    const int n0 = (grp << 10) + threadIdx.x;

    float    a0, a1, a2, a3;
    unsigned p0, p1, p2, p3;
    {
        PN c0 = wp[tbase + n0];         // 4 coalesced loads
        PN c1 = wp[tbase + n0 + 256];
        PN c2 = wp[tbase + n0 + 512];
        PN c3 = wp[tbase + n0 + 768];
        a0 = pn_w(c0); p0 = pn_p(c0);
        a1 = pn_w(c1); p1 = pn_p(c1);
        a2 = pn_w(c2); p2 = pn_p(c2);
        a3 = pn_w(c3); p3 = pn_p(c3);
    }
    // lockstep: up to 4 independent L2 loads issued per iteration
    while ((p0 >= MLOW) | (p1 >= MLOW) | (p2 >= MLOW) | (p3 >= MLOW)) {
        if (p0 >= MLOW) { PN nx = wp[tbase + p0]; a0 += pn_w(nx); p0 = pn_p(nx); }
        if (p1 >= MLOW) { PN nx = wp[tbase + p1]; a1 += pn_w(nx); p1 = pn_p(nx); }
        if (p2 >= MLOW) { PN nx = wp[tbase + p2]; a2 += pn_w(nx); p2 = pn_p(nx); }
        if (p3 >= MLOW) { PN nx = wp[tbase + p3]; a3 += pn_w(nx); p3 = pn_p(nx); }
    }
    // vlow window is 32 KB -> L1-resident random reads
    valh[tbase + n0      ] = f2bf(a0 + vlow[p0]);
    valh[tbase + n0 + 256] = f2bf(a1 + vlow[p1]);
    valh[tbase + n0 + 512] = f2bf(a2 + vlow[p2]);
    valh[tbase + n0 + 768] = f2bf(a3 + vlow[p3]);
}

// Kernel 4: out[i] = val[bn, pix2cc[i]] / 10. Whole tree's bf16 val table
// (128 KB) staged in LDS; pix/out are pure nontemporal HBM streams.
// Load order matters: stage loads issue FIRST (oldest in vmcnt order), then
// all 8 pixel int4 loads; the ds_writes then wait only on the stage loads
// (vmcnt(8)) while pixel HBM latency keeps hiding under stage + barrier.
__global__ __launch_bounds__(1024) void k_gather(
    const unsigned short* __restrict__ valh, const int* __restrict__ pix,
    float* __restrict__ out)
{
    __shared__ unsigned short sval[CC]; // 128 KB of 160 KB/CU
    const int bid  = blockIdx.x;            // 0..255
    const int x    = bid & 7;
    const int r    = bid >> 3;              // 0..31
    const int tree = (x << 2) + (r & 3);    // same XCD as k_chain's writer
    const int seg  = r >> 2;                // 0..7
    const int tid  = threadIdx.x;

    // 1) stage loads to regs (8192 uint4; 1024 threads x 8, coalesced, L2-hit)
    const uint4* s4 = (const uint4*)(valh + ((long long)tree << 16));
    uint4 st[8];
    #pragma unroll
    for (int i = 0; i < 8; ++i)
        st[i] = s4[tid + i * 1024];

    // 2) pixel loads issued now -> in flight across ds_writes + barrier
    const long long pbase = ((long long)tree << 18) + ((long long)seg << 15);
    const nint4*   psrc = (const nint4*)(pix + pbase);
    nfloat4*       pdst = (nfloat4*)(out + pbase);
    nint4 cc[8];
    #pragma unroll
    for (int it = 0; it < 8; ++it)
        cc[it] = __builtin_nontemporal_load(psrc + tid + it * 1024);

    // 3) park stage into LDS (waits only on stage loads: they are oldest)
    uint4* d4 = (uint4*)sval;
    #pragma unroll
    for (int i = 0; i < 8; ++i)
        d4[tid + i * 1024] = st[i];
    __syncthreads();

    // 4) gather + stream out
    #pragma unroll
    for (int it = 0; it < 8; ++it) {
        nfloat4 o;
        o.x = bf2f(sval[cc[it].x]) * 0.1f;
        o.y = bf2f(sval[cc[it].y]) * 0.1f;
        o.z = bf2f(sval[cc[it].z]) * 0.1f;
        o.w = bf2f(sval[cc[it].w]) * 0.1f;
        __builtin_nontemporal_store(o, pdst + tid + it * 1024);
    }
}

extern "C" void kernel_launch(void* const* d_in, const int* in_sizes, int n_in,
                              void* d_out, int out_size, void* d_ws, size_t ws_size,
                              hipStream_t stream) {
    const float* diff   = (const float*)d_in[0];
    const float* attrs  = (const float*)d_in[1];
    const float* weight = (const float*)d_in[2];
    const float* bias   = (const float*)d_in[3];
    const int*   parent = (const int*)d_in[4];
    const int*   pix    = (const int*)d_in[5];
    float* out = (float*)d_out;

    // ws layout: [wp packed: 8MB][valh: 4MB][valLow: 1MB]
    PN*             wp     = (PN*)d_ws;
    unsigned short* valh   = (unsigned short*)((char*)d_ws + (size_t)BB * NN * CC * sizeof(PN));
    float*          valLow = (float*)((char*)valh + (size_t)BB * NN * CC * sizeof(unsigned short));

    const long long total = (long long)BB * NN * CC;      // 2,097,152

    k_score <<<(int)(total / 256), 256, 0, stream>>>(diff, attrs, weight, bias, parent, wp);
    k_low   <<<(BB * NN * MLOW) / 256, 256, 0, stream>>>(wp, valLow, valh);
    k_chain <<<BB * NN * 56, 256, 0, stream>>>(wp, valLow, valh);
    k_gather<<<BB * NN * 8, 1024, 0, stream>>>(valh, pix, out);
}